// Round 1
// baseline (311.652 us; speedup 1.0000x reference)
//
#include <hip/hip_runtime.h>
#include <cstdint>

typedef unsigned short u16;
typedef unsigned int u32;

// MFMA fragment types (per cdna_hip_programming.md §3)
typedef short bf16x8 __attribute__((ext_vector_type(8)));
typedef float f32x4 __attribute__((ext_vector_type(4)));

#define LN2 0.69314718055994530942f

__device__ __forceinline__ u16 f2bf(float f) {
  u32 u = __float_as_uint(f);
  u = (u + 0x7fffu + ((u >> 16) & 1u)) >> 16;
  return (u16)u;
}
__device__ __forceinline__ float bf2f(u16 h) {
  return __uint_as_float(((u32)h) << 16);
}

// ---------------- prep kernels ----------------

__global__ void k_convert_x(const float* __restrict__ in, u16* __restrict__ out, int n4) {
  int i = blockIdx.x * blockDim.x + threadIdx.x;
  if (i < n4) {
    float4 v = ((const float4*)in)[i];
    ushort4 o;
    o.x = f2bf(v.x); o.y = f2bf(v.y); o.z = f2bf(v.z); o.w = f2bf(v.w);
    ((ushort4*)out)[i] = o;
  }
}

// in: (R, C) fp32 row-major  ->  out: (C, R) bf16 row-major
__global__ void k_transpose_bf(const float* __restrict__ in, u16* __restrict__ out, int R, int C) {
  __shared__ float t[32][33];
  int c0 = blockIdx.x * 32, r0 = blockIdx.y * 32;
  int tx = threadIdx.x, ty = threadIdx.y;
#pragma unroll
  for (int k = 0; k < 4; k++) t[ty + 8 * k][tx] = in[(size_t)(r0 + ty + 8 * k) * C + c0 + tx];
  __syncthreads();
#pragma unroll
  for (int k = 0; k < 4; k++) out[(size_t)(c0 + ty + 8 * k) * R + r0 + tx] = f2bf(t[tx][ty + 8 * k]);
}

// ig2[t] = ln2 / (ln(|c*max(t,thr)|+1) + 1e-6)
__global__ void k_tables(const float* __restrict__ cP, const float* __restrict__ lP,
                         float* __restrict__ ig2) {
  int t = blockIdx.x * blockDim.x + threadIdx.x;
  if (t < 2048) {
    float c = cP[0], lm = lP[0];
    float thr = fabsf(lm * 512.0f);
    float pn = fmaxf((float)t, thr);
    float den = logf(fabsf(c * pn) + 1.0f) + 1e-6f;
    ig2[t] = LN2 / den;
  }
}

// Piecewise-linear decomposition of the FIRE MLP:
// bias_h(nd) = segA[j][h] + nd * segB[j][h] on segment j, breakpoints segX.
__global__ void k_segments(const float* __restrict__ w1, const float* __restrict__ b1,
                           const float* __restrict__ w2, const float* __restrict__ b2,
                           float* __restrict__ segX, float* __restrict__ segA,
                           float* __restrict__ segB, int* __restrict__ segU) {
  __shared__ float xs[32];
  __shared__ float srt[32];
  __shared__ float uniq[32];
  __shared__ int uCnt;
  int t = threadIdx.x;
  if (t < 32) {
    float w = w1[t], b = b1[t];
    xs[t] = (w != 0.0f) ? (-b / w) : __builtin_inff();
  }
  __syncthreads();
  if (t < 32) {
    float x = xs[t];
    int r = 0;
    for (int v = 0; v < 32; v++) {
      float xv = xs[v];
      if (xv < x || (xv == x && v < t)) r++;
    }
    srt[r] = x;
  }
  __syncthreads();
  if (t == 0) {
    int u = 0;
    for (int i = 0; i < 32; i++) {
      float v = srt[i];
      if (v < 3.0e38f && (u == 0 || v != uniq[u - 1])) uniq[u++] = v;
    }
    uCnt = u;
    segU[0] = u;
  }
  __syncthreads();
  int u = uCnt;
  if (t < u) segX[t] = uniq[t];
  for (int idx = t; idx < (u + 1) * 16; idx += blockDim.x) {
    int j = idx >> 4, h = idx & 15;
    float p;
    if (u == 0) p = 0.0f;
    else if (j == 0) p = uniq[0] - 1.0f;
    else if (j == u) p = uniq[u - 1] + 1.0f;
    else p = 0.5f * (uniq[j - 1] + uniq[j]);
    float A = b2[h], B = 0.0f;
    for (int w = 0; w < 32; w++) {
      float w1w = w1[w], b1w = b1[w], w2wh = w2[w * 16 + h];
      if (w1w != 0.0f) {
        if (fmaf(w1w, p, b1w) > 0.0f) { B += w1w * w2wh; A += b1w * w2wh; }
      } else if (b1w > 0.0f) {
        A += b1w * w2wh;
      }
    }
    segA[j * 16 + h] = A;
    segB[j * 16 + h] = B;
  }
}

// ---------------- GEMM:  C(MxN) = A(MxK) @ BT(NxK)^T ----------------
// MODE 0: QKV -> scatter to Q/K/V (B,H,T,hd) bf16, +bqkv
// MODE 1: proj -> fp32 out, +bproj
template <int MODE>
__launch_bounds__(256, 2)
__global__ void k_gemm(const u16* __restrict__ A, const u16* __restrict__ BT,
                       const float* __restrict__ bias, float* __restrict__ outF,
                       u16* __restrict__ outQ, u16* __restrict__ outK, u16* __restrict__ outV,
                       int M, int N, int K) {
  __shared__ u16 As[128][72];  // 144B row stride: 16B aligned, even bank spread
  __shared__ u16 Bs[128][72];
  const int tid = threadIdx.x;
  const int lane = tid & 63, wave = tid >> 6;
  const int li = lane & 15, quad = lane >> 4;
  const int wrow = (wave >> 1) * 64, wcol = (wave & 1) * 64;
  const int rb = blockIdx.y * 128, cb = blockIdx.x * 128;
  const int srow = tid >> 1, shalf = tid & 1;

  f32x4 acc[4][4];
#pragma unroll
  for (int i = 0; i < 4; i++)
#pragma unroll
    for (int j = 0; j < 4; j++) acc[i][j] = (f32x4){0.f, 0.f, 0.f, 0.f};

  const u16* gA = A + (size_t)(rb + srow) * K + shalf * 32;
  const u16* gB = BT + (size_t)(cb + srow) * K + shalf * 32;

  for (int k0 = 0; k0 < K; k0 += 64) {
    uint4 a0 = *(const uint4*)(gA + k0);
    uint4 a1 = *(const uint4*)(gA + k0 + 8);
    uint4 a2 = *(const uint4*)(gA + k0 + 16);
    uint4 a3 = *(const uint4*)(gA + k0 + 24);
    uint4 b0 = *(const uint4*)(gB + k0);
    uint4 b1 = *(const uint4*)(gB + k0 + 8);
    uint4 b2v = *(const uint4*)(gB + k0 + 16);
    uint4 b3 = *(const uint4*)(gB + k0 + 24);
    __syncthreads();
    *(uint4*)(&As[srow][shalf * 32]) = a0;
    *(uint4*)(&As[srow][shalf * 32 + 8]) = a1;
    *(uint4*)(&As[srow][shalf * 32 + 16]) = a2;
    *(uint4*)(&As[srow][shalf * 32 + 24]) = a3;
    *(uint4*)(&Bs[srow][shalf * 32]) = b0;
    *(uint4*)(&Bs[srow][shalf * 32 + 8]) = b1;
    *(uint4*)(&Bs[srow][shalf * 32 + 16]) = b2v;
    *(uint4*)(&Bs[srow][shalf * 32 + 24]) = b3;
    __syncthreads();
#pragma unroll
    for (int c = 0; c < 2; c++) {
      bf16x8 af[4], bfr[4];
#pragma unroll
      for (int mt = 0; mt < 4; mt++)
        af[mt] = *(const bf16x8*)(&As[wrow + mt * 16 + li][c * 32 + quad * 8]);
#pragma unroll
      for (int nt = 0; nt < 4; nt++)
        bfr[nt] = *(const bf16x8*)(&Bs[wcol + nt * 16 + li][c * 32 + quad * 8]);
#pragma unroll
      for (int mt = 0; mt < 4; mt++)
#pragma unroll
        for (int nt = 0; nt < 4; nt++)
          acc[mt][nt] = __builtin_amdgcn_mfma_f32_16x16x32_bf16(af[mt], bfr[nt], acc[mt][nt], 0, 0, 0);
    }
  }

#pragma unroll
  for (int mt = 0; mt < 4; mt++)
#pragma unroll
    for (int nt = 0; nt < 4; nt++)
#pragma unroll
      for (int r = 0; r < 4; r++) {
        int row = rb + wrow + mt * 16 + quad * 4 + r;
        int col = cb + wcol + nt * 16 + li;
        float v = acc[mt][nt][r] + bias[col];
        if (MODE == 0) {
          int b = row >> 11, tt = row & 2047;
          int sel = col >> 10, w = col & 1023, h = w >> 6, dd = w & 63;
          u16* dst = (sel == 0) ? outQ : ((sel == 1) ? outK : outV);
          dst[(size_t)((b * 16 + h) * 2048 + tt) * 64 + dd] = f2bf(v);
        } else {
          outF[(size_t)row * N + col] = v;
        }
      }
}

// ---------------- flash attention with on-the-fly FIRE bias ----------------
__launch_bounds__(256, 2)
__global__ void k_attn(const u16* __restrict__ Q, const u16* __restrict__ K,
                       const u16* __restrict__ V, u16* __restrict__ Y,
                       const float* __restrict__ ig2, const float* __restrict__ segX,
                       const float* __restrict__ segA, const float* __restrict__ segB,
                       const int* __restrict__ segU, const float* __restrict__ cP) {
  __shared__ u16 Ks[64][72];
  __shared__ u16 Vts[64][72];  // transposed: Vts[d][kk]
  __shared__ u16 Ps[64][72];
  __shared__ float sXl[32];
  __shared__ float sAl[33];
  __shared__ float sBl[33];

  const int qt = blockIdx.x, h = blockIdx.y, b = blockIdx.z;
  const int tid = threadIdx.x, lane = tid & 63, wave = tid >> 6;
  const int li = lane & 15, quad = lane >> 4;
  const int bh = b * 16 + h;
  const u16* Qg = Q + (size_t)bh * 2048 * 64;
  const u16* Kg = K + (size_t)bh * 2048 * 64;
  const u16* Vg = V + (size_t)bh * 2048 * 64;
  const int qw = qt * 64 + wave * 16;

  const float ca = fabsf(cP[0]);
  const int u = segU[0];
  float x0 = __builtin_inff(), A0, B0, A1, B1;
  A0 = segA[h]; B0 = segB[h]; A1 = A0; B1 = B0;
  if (u == 1) { x0 = segX[0]; A1 = segA[16 + h]; B1 = segB[16 + h]; }
  if (u > 1) {
    if (tid < u) sXl[tid] = segX[tid];
    if (tid < u + 1) { sAl[tid] = segA[tid * 16 + h]; sBl[tid] = segB[tid * 16 + h]; }
  }
  __syncthreads();

  // Q fragments straight from global (A-layout: m=li, k=quad*8+j)
  bf16x8 qf[2];
#pragma unroll
  for (int c = 0; c < 2; c++)
    qf[c] = *(const bf16x8*)(Qg + (size_t)(qw + li) * 64 + c * 32 + quad * 8);

  float tF[4], gI[4], mrow[4], lrow[4];
#pragma unroll
  for (int r = 0; r < 4; r++) {
    int t = qw + quad * 4 + r;
    tF[r] = (float)t;
    gI[r] = ig2[t];
    mrow[r] = -__builtin_inff();
    lrow[r] = 0.0f;
  }
  f32x4 oacc[4];
#pragma unroll
  for (int nt = 0; nt < 4; nt++) oacc[nt] = (f32x4){0.f, 0.f, 0.f, 0.f};

  for (int kt = 0; kt <= qt; kt++) {
    const int kb = kt * 64;
    // stage K straight, V transposed (pair-packed b32 writes)
    {
      const u16* ksrc = Kg + (size_t)(kb + (tid >> 2)) * 64 + (tid & 3) * 16;
      uint4 kv0 = *(const uint4*)(ksrc);
      uint4 kv1 = *(const uint4*)(ksrc + 8);
      const int kkp = tid & 31, d0 = (tid >> 5) * 8;
      const u16* vsrc0 = Vg + (size_t)(kb + 2 * kkp) * 64 + d0;
      uint4 w0 = *(const uint4*)(vsrc0);
      uint4 w1 = *(const uint4*)(vsrc0 + 64);
      __syncthreads();
      *(uint4*)(&Ks[tid >> 2][(tid & 3) * 16]) = kv0;
      *(uint4*)(&Ks[tid >> 2][(tid & 3) * 16 + 8]) = kv1;
      const u16* pw0 = (const u16*)&w0;
      const u16* pw1 = (const u16*)&w1;
#pragma unroll
      for (int j = 0; j < 8; j++) {
        u32 pk = (u32)pw0[j] | ((u32)pw1[j] << 16);
        *(u32*)(&Vts[d0 + j][2 * kkp]) = pk;
      }
      __syncthreads();
    }

    // S = Q K^T
    f32x4 sacc[4];
#pragma unroll
    for (int nt = 0; nt < 4; nt++) sacc[nt] = (f32x4){0.f, 0.f, 0.f, 0.f};
#pragma unroll
    for (int c = 0; c < 2; c++)
#pragma unroll
      for (int nt = 0; nt < 4; nt++) {
        bf16x8 kf = *(const bf16x8*)(&Ks[nt * 16 + li][c * 32 + quad * 8]);
        sacc[nt] = __builtin_amdgcn_mfma_f32_16x16x32_bf16(qf[c], kf, sacc[nt], 0, 0, 0);
      }

    // scale + FIRE bias (+ causal mask)
#pragma unroll
    for (int nt = 0; nt < 4; nt++) {
      float sF = (float)(kb + nt * 16 + li);
#pragma unroll
      for (int r = 0; r < 4; r++) {
        float dF = tF[r] - sF;
        float bv;
        if (dF < 0.0f) {
          bv = -__builtin_inff();
        } else {
          float nd = __log2f(fmaf(ca, dF, 1.0f)) * gI[r];
          if (u <= 1) {
            bool hi = nd > x0;
            bv = fmaf(nd, hi ? B1 : B0, hi ? A1 : A0);
          } else {
            int j = 0;
            for (int i = 0; i < u; i++) j += (nd > sXl[i]) ? 1 : 0;
            bv = fmaf(nd, sBl[j], sAl[j]);
          }
        }
        sacc[nt][r] = fmaf(sacc[nt][r], 0.125f, bv);
      }
    }

    // online softmax
#pragma unroll
    for (int r = 0; r < 4; r++) {
      float vm = fmaxf(fmaxf(sacc[0][r], sacc[1][r]), fmaxf(sacc[2][r], sacc[3][r]));
#pragma unroll
      for (int off = 1; off < 16; off <<= 1) vm = fmaxf(vm, __shfl_xor(vm, off, 64));
      float mnew = fmaxf(mrow[r], vm);
      float alpha = __expf(mrow[r] - mnew);
      mrow[r] = mnew;
      float s = 0.0f;
#pragma unroll
      for (int nt = 0; nt < 4; nt++) {
        float p = __expf(sacc[nt][r] - mnew);
        sacc[nt][r] = p;
        s += p;
      }
#pragma unroll
      for (int off = 1; off < 16; off <<= 1) s += __shfl_xor(s, off, 64);
      lrow[r] = lrow[r] * alpha + s;
#pragma unroll
      for (int nt = 0; nt < 4; nt++) oacc[nt][r] *= alpha;
    }

    // P -> LDS (C-layout -> A-layout transform); same-wave rows only
#pragma unroll
    for (int nt = 0; nt < 4; nt++)
#pragma unroll
      for (int r = 0; r < 4; r++)
        Ps[wave * 16 + quad * 4 + r][nt * 16 + li] = f2bf(sacc[nt][r]);

    // O += P V
#pragma unroll
    for (int c = 0; c < 2; c++) {
      bf16x8 pf = *(const bf16x8*)(&Ps[wave * 16 + li][c * 32 + quad * 8]);
#pragma unroll
      for (int nt = 0; nt < 4; nt++) {
        bf16x8 vf = *(const bf16x8*)(&Vts[nt * 16 + li][c * 32 + quad * 8]);
        oacc[nt] = __builtin_amdgcn_mfma_f32_16x16x32_bf16(pf, vf, oacc[nt], 0, 0, 0);
      }
    }
  }

  // epilogue: normalize, write y in (B,T,H*hd) bf16
#pragma unroll
  for (int r = 0; r < 4; r++) {
    float inv = 1.0f / lrow[r];
    int t = qw + quad * 4 + r;
    u16* dst = Y + (size_t)(b * 2048 + t) * 1024 + h * 64;
#pragma unroll
    for (int nt = 0; nt < 4; nt++) dst[nt * 16 + li] = f2bf(oacc[nt][r] * inv);
  }
}

// ---------------- launcher ----------------
extern "C" void kernel_launch(void* const* d_in, const int* in_sizes, int n_in,
                              void* d_out, int out_size, void* d_ws, size_t ws_size,
                              hipStream_t stream) {
  (void)in_sizes; (void)n_in; (void)out_size; (void)ws_size;
  const float* x = (const float*)d_in[0];
  const float* Wqkv = (const float*)d_in[1];
  const float* bqkv = (const float*)d_in[2];
  const float* Wproj = (const float*)d_in[3];
  const float* bproj = (const float*)d_in[4];
  const float* w1 = (const float*)d_in[5];
  const float* b1 = (const float*)d_in[6];
  const float* w2 = (const float*)d_in[7];
  const float* b2 = (const float*)d_in[8];
  const float* cP = (const float*)d_in[9];
  const float* lP = (const float*)d_in[10];

  char* ws = (char*)d_ws;
  u16* Xbf = (u16*)(ws);                          // 8 MB
  u16* WqkvT = (u16*)(ws + (size_t)(8 << 20));    // 6 MB
  u16* WprojT = (u16*)(ws + (size_t)(14 << 20));  // 2 MB
  u16* Qb = (u16*)(ws + (size_t)(16 << 20));      // 8 MB
  u16* Kb = (u16*)(ws + (size_t)(24 << 20));      // 8 MB
  u16* Vb = (u16*)(ws + (size_t)(32 << 20));      // 8 MB
  u16* Yb = (u16*)(ws + (size_t)(40 << 20));      // 8 MB
  float* IG = (float*)(ws + (size_t)(48 << 20));  // 8 KB
  float* SEGX = IG + 2048;
  float* SEGA = SEGX + 32;
  float* SEGB = SEGA + 33 * 16;
  int* SEGU = (int*)(SEGB + 33 * 16);

  k_convert_x<<<4096, 256, 0, stream>>>(x, Xbf, 1048576);
  k_transpose_bf<<<dim3(96, 32), dim3(32, 8), 0, stream>>>(Wqkv, WqkvT, 1024, 3072);
  k_transpose_bf<<<dim3(32, 32), dim3(32, 8), 0, stream>>>(Wproj, WprojT, 1024, 1024);
  k_tables<<<8, 256, 0, stream>>>(cP, lP, IG);
  k_segments<<<1, 64, 0, stream>>>(w1, b1, w2, b2, SEGX, SEGA, SEGB, SEGU);

  k_gemm<0><<<dim3(24, 32), 256, 0, stream>>>(Xbf, WqkvT, bqkv, nullptr, Qb, Kb, Vb,
                                              4096, 3072, 1024);
  k_attn<<<dim3(32, 16, 2), 256, 0, stream>>>(Qb, Kb, Vb, Yb, IG, SEGX, SEGA, SEGB, SEGU, cP);
  k_gemm<1><<<dim3(8, 32), 256, 0, stream>>>(Yb, WprojT, bproj, (float*)d_out, nullptr, nullptr,
                                             nullptr, 4096, 1024, 1024);
}

// Round 2
// 256.313 us; speedup vs baseline: 1.2159x; 1.2159x over previous
//
#include <hip/hip_runtime.h>
#include <cstdint>

typedef unsigned short u16;
typedef unsigned int u32;

typedef short bf16x8 __attribute__((ext_vector_type(8)));
typedef float f32x4 __attribute__((ext_vector_type(4)));

#define LN2 0.69314718055994530942f
#define LOG2E 1.44269504088896340736f
#define INFF __builtin_inff()

__device__ __forceinline__ u16 f2bf(float f) {
  u32 u = __float_as_uint(f);
  u = (u + 0x7fffu + ((u >> 16) & 1u)) >> 16;
  return (u16)u;
}
// cheap round-to-nearest (no tie-to-even): 2 ops
__device__ __forceinline__ u16 f2bfr(float f) {
  return (u16)((__float_as_uint(f) + 0x8000u) >> 16);
}

// ---------------- prep kernels ----------------

__global__ void k_convert_x(const float* __restrict__ in, u16* __restrict__ out, int n4) {
  int i = blockIdx.x * blockDim.x + threadIdx.x;
  if (i < n4) {
    float4 v = ((const float4*)in)[i];
    ushort4 o;
    o.x = f2bf(v.x); o.y = f2bf(v.y); o.z = f2bf(v.z); o.w = f2bf(v.w);
    ((ushort4*)out)[i] = o;
  }
}

__global__ void k_transpose_bf(const float* __restrict__ in, u16* __restrict__ out, int R, int C) {
  __shared__ float t[32][33];
  int c0 = blockIdx.x * 32, r0 = blockIdx.y * 32;
  int tx = threadIdx.x, ty = threadIdx.y;
#pragma unroll
  for (int k = 0; k < 4; k++) t[ty + 8 * k][tx] = in[(size_t)(r0 + ty + 8 * k) * C + c0 + tx];
  __syncthreads();
#pragma unroll
  for (int k = 0; k < 4; k++) out[(size_t)(c0 + ty + 8 * k) * R + r0 + tx] = f2bf(t[tx][ty + 8 * k]);
}

// ig2[t] = ln2 / (ln(|c|*max(t,thr)+1) + 1e-6) ; rl[j] = log2(|c|*max(j-63,0)+1)
__global__ void k_tables(const float* __restrict__ cP, const float* __restrict__ lP,
                         float* __restrict__ ig2, float* __restrict__ rl) {
  int t = blockIdx.x * blockDim.x + threadIdx.x;
  float c = fabsf(cP[0]);
  if (t < 2048) {
    float lm = lP[0];
    float thr = fabsf(lm * 512.0f);
    float pn = fmaxf((float)t, thr);
    float den = logf(c * pn + 1.0f) + 1e-6f;
    ig2[t] = LN2 / den;
  }
  if (t < 2112) {
    int d = t - 63;
    if (d < 0) d = 0;
    rl[t] = log2f(c * (float)d + 1.0f);
  }
}

// Piecewise-linear decomposition of the FIRE MLP.
__global__ void k_segments(const float* __restrict__ w1, const float* __restrict__ b1,
                           const float* __restrict__ w2, const float* __restrict__ b2,
                           float* __restrict__ segX, float* __restrict__ segA,
                           float* __restrict__ segB, int* __restrict__ segU) {
  __shared__ float xs[32];
  __shared__ float srt[32];
  __shared__ float uniq[32];
  __shared__ int uCnt;
  int t = threadIdx.x;
  if (t < 32) {
    float w = w1[t], b = b1[t];
    xs[t] = (w != 0.0f) ? (-b / w) : INFF;
  }
  __syncthreads();
  if (t < 32) {
    float x = xs[t];
    int r = 0;
    for (int v = 0; v < 32; v++) {
      float xv = xs[v];
      if (xv < x || (xv == x && v < t)) r++;
    }
    srt[r] = x;
  }
  __syncthreads();
  if (t == 0) {
    int u = 0;
    for (int i = 0; i < 32; i++) {
      float v = srt[i];
      if (v < 3.0e38f && (u == 0 || v != uniq[u - 1])) uniq[u++] = v;
    }
    uCnt = u;
    segU[0] = u;
  }
  __syncthreads();
  int u = uCnt;
  if (t < u) segX[t] = uniq[t];
  for (int idx = t; idx < (u + 1) * 16; idx += blockDim.x) {
    int j = idx >> 4, h = idx & 15;
    float p;
    if (u == 0) p = 0.0f;
    else if (j == 0) p = uniq[0] - 1.0f;
    else if (j == u) p = uniq[u - 1] + 1.0f;
    else p = 0.5f * (uniq[j - 1] + uniq[j]);
    float A = b2[h], B = 0.0f;
    for (int w = 0; w < 32; w++) {
      float w1w = w1[w], b1w = b1[w], w2wh = w2[w * 16 + h];
      if (w1w != 0.0f) {
        if (fmaf(w1w, p, b1w) > 0.0f) { B += w1w * w2wh; A += b1w * w2wh; }
      } else if (b1w > 0.0f) {
        A += b1w * w2wh;
      }
    }
    segA[j * 16 + h] = A;
    segB[j * 16 + h] = B;
  }
}

// ---------------- GEMM:  C(MxN) = A(MxK) @ BT(NxK)^T ----------------
template <int MODE>
__launch_bounds__(256, 3)
__global__ void k_gemm(const u16* __restrict__ A, const u16* __restrict__ BT,
                       const float* __restrict__ bias, float* __restrict__ outF,
                       u16* __restrict__ outQ, u16* __restrict__ outK, u16* __restrict__ outV,
                       int M, int N, int K) {
  __shared__ u16 As[128][72];
  __shared__ u16 Bs[128][72];
  const int tid = threadIdx.x;
  const int lane = tid & 63, wave = tid >> 6;
  const int li = lane & 15, quad = lane >> 4;
  const int wrow = (wave >> 1) * 64, wcol = (wave & 1) * 64;
  const int rb = blockIdx.y * 128, cb = blockIdx.x * 128;
  const int srow = tid >> 1, shalf = tid & 1;

  f32x4 acc[4][4];
#pragma unroll
  for (int i = 0; i < 4; i++)
#pragma unroll
    for (int j = 0; j < 4; j++) acc[i][j] = (f32x4){0.f, 0.f, 0.f, 0.f};

  const u16* gA = A + (size_t)(rb + srow) * K + shalf * 32;
  const u16* gB = BT + (size_t)(cb + srow) * K + shalf * 32;

  for (int k0 = 0; k0 < K; k0 += 64) {
    uint4 a0 = *(const uint4*)(gA + k0);
    uint4 a1 = *(const uint4*)(gA + k0 + 8);
    uint4 a2 = *(const uint4*)(gA + k0 + 16);
    uint4 a3 = *(const uint4*)(gA + k0 + 24);
    uint4 b0 = *(const uint4*)(gB + k0);
    uint4 b1 = *(const uint4*)(gB + k0 + 8);
    uint4 b2v = *(const uint4*)(gB + k0 + 16);
    uint4 b3 = *(const uint4*)(gB + k0 + 24);
    __syncthreads();
    *(uint4*)(&As[srow][shalf * 32]) = a0;
    *(uint4*)(&As[srow][shalf * 32 + 8]) = a1;
    *(uint4*)(&As[srow][shalf * 32 + 16]) = a2;
    *(uint4*)(&As[srow][shalf * 32 + 24]) = a3;
    *(uint4*)(&Bs[srow][shalf * 32]) = b0;
    *(uint4*)(&Bs[srow][shalf * 32 + 8]) = b1;
    *(uint4*)(&Bs[srow][shalf * 32 + 16]) = b2v;
    *(uint4*)(&Bs[srow][shalf * 32 + 24]) = b3;
    __syncthreads();
#pragma unroll
    for (int c = 0; c < 2; c++) {
      bf16x8 af[4], bfr[4];
#pragma unroll
      for (int mt = 0; mt < 4; mt++)
        af[mt] = *(const bf16x8*)(&As[wrow + mt * 16 + li][c * 32 + quad * 8]);
#pragma unroll
      for (int nt = 0; nt < 4; nt++)
        bfr[nt] = *(const bf16x8*)(&Bs[wcol + nt * 16 + li][c * 32 + quad * 8]);
#pragma unroll
      for (int mt = 0; mt < 4; mt++)
#pragma unroll
        for (int nt = 0; nt < 4; nt++)
          acc[mt][nt] = __builtin_amdgcn_mfma_f32_16x16x32_bf16(af[mt], bfr[nt], acc[mt][nt], 0, 0, 0);
    }
  }

#pragma unroll
  for (int mt = 0; mt < 4; mt++)
#pragma unroll
    for (int nt = 0; nt < 4; nt++)
#pragma unroll
      for (int r = 0; r < 4; r++) {
        int row = rb + wrow + mt * 16 + quad * 4 + r;
        int col = cb + wcol + nt * 16 + li;
        float v = acc[mt][nt][r] + bias[col];
        if (MODE == 0) {
          int b = row >> 11, tt = row & 2047;
          int sel = col >> 10, w = col & 1023, h = w >> 6, dd = w & 63;
          u16* dst = (sel == 0) ? outQ : ((sel == 1) ? outK : outV);
          dst[(size_t)((b * 16 + h) * 2048 + tt) * 64 + dd] = f2bf(v);
        } else {
          outF[(size_t)row * N + col] = v;
        }
      }
}

// ---------------- flash attention, paired q-tiles, dbuf staging, rl-table bias ----------------
__launch_bounds__(256, 2)
__global__ void k_attn(const u16* __restrict__ Q, const u16* __restrict__ K,
                       const u16* __restrict__ V, u16* __restrict__ Y,
                       const float* __restrict__ ig2, const float* __restrict__ RL,
                       const float* __restrict__ segX, const float* __restrict__ segA,
                       const float* __restrict__ segB, const int* __restrict__ segU) {
  __shared__ u16 Ks[2][64][72];
  __shared__ u16 Vts[2][64][72];
  __shared__ u16 Ps[64][72];
  __shared__ float rls[2112];
  __shared__ float sXl[32];
  __shared__ float sAl[33];
  __shared__ float sBl[33];

  const int pr = blockIdx.x, h = blockIdx.y, b = blockIdx.z;
  const int tid = threadIdx.x, lane = tid & 63, wave = tid >> 6;
  const int li = lane & 15, quad = lane >> 4;
  const int bh = b * 16 + h;
  const u16* Qg = Q + (size_t)bh * 2048 * 64;
  const u16* Kg = K + (size_t)bh * 2048 * 64;
  const u16* Vg = V + (size_t)bh * 2048 * 64;

  for (int i = tid; i < 2112; i += 256) rls[i] = RL[i];

  const int u = segU[0];
  float x0 = INFF, A0, B0, A1, B1;
  A0 = segA[h]; B0 = segB[h]; A1 = A0; B1 = B0;
  if (u == 1) { x0 = segX[0]; A1 = segA[16 + h]; B1 = segB[16 + h]; }
  if (u > 1) {
    if (tid < u) sXl[tid] = segX[tid];
    if (tid < u + 1) { sAl[tid] = segA[tid * 16 + h]; sBl[tid] = segB[tid * 16 + h]; }
  }
  const float A0e = A0 * LOG2E, A1e = A1 * LOG2E;
  const float SCL = 0.125f * LOG2E;

  auto run_tile = [&](int qt) {
    const int qw = qt * 64 + wave * 16;
    bf16x8 qf[2];
#pragma unroll
    for (int c = 0; c < 2; c++)
      qf[c] = *(const bf16x8*)(Qg + (size_t)(qw + li) * 64 + c * 32 + quad * 8);

    int ti[4];
    float gI[4], x0r[4], B0g[4], B1g[4], mrow[4], lrow[4];
#pragma unroll
    for (int r = 0; r < 4; r++) {
      ti[r] = qw + quad * 4 + r;
      gI[r] = ig2[ti[r]];
      x0r[r] = x0 / gI[r];
      B0g[r] = B0 * gI[r] * LOG2E;
      B1g[r] = B1 * gI[r] * LOG2E;
      mrow[r] = -INFF;
      lrow[r] = 0.0f;
    }
    f32x4 oacc[4];
#pragma unroll
    for (int nt = 0; nt < 4; nt++) oacc[nt] = (f32x4){0.f, 0.f, 0.f, 0.f};

    // prefetch kt = 0 into registers
    uint4 kv0, kv1, w0, w1;
    {
      const u16* ksrc = Kg + (size_t)(tid >> 2) * 64 + (tid & 3) * 16;
      kv0 = *(const uint4*)(ksrc);
      kv1 = *(const uint4*)(ksrc + 8);
      const u16* vsrc = Vg + (size_t)(2 * (tid & 31)) * 64 + (tid >> 5) * 8;
      w0 = *(const uint4*)(vsrc);
      w1 = *(const uint4*)(vsrc + 64);
    }
    __syncthreads();  // protect LDS buffers from previous tile's readers

    for (int kt = 0; kt <= qt; kt++) {
      const int kb = kt * 64, buf = kt & 1;
      // write staged K/V to LDS
      *(uint4*)(&Ks[buf][tid >> 2][(tid & 3) * 16]) = kv0;
      *(uint4*)(&Ks[buf][tid >> 2][(tid & 3) * 16 + 8]) = kv1;
      {
        const int kkp = tid & 31, d0 = (tid >> 5) * 8;
        const u16* pw0 = (const u16*)&w0;
        const u16* pw1 = (const u16*)&w1;
#pragma unroll
        for (int j = 0; j < 8; j++)
          *(u32*)(&Vts[buf][d0 + j][2 * kkp]) = (u32)pw0[j] | ((u32)pw1[j] << 16);
      }
      __syncthreads();
      if (kt < qt) {  // prefetch next tile while computing this one
        const u16* ksrc = Kg + (size_t)(kb + 64 + (tid >> 2)) * 64 + (tid & 3) * 16;
        kv0 = *(const uint4*)(ksrc);
        kv1 = *(const uint4*)(ksrc + 8);
        const u16* vsrc = Vg + (size_t)(kb + 64 + 2 * (tid & 31)) * 64 + (tid >> 5) * 8;
        w0 = *(const uint4*)(vsrc);
        w1 = *(const uint4*)(vsrc + 64);
      }

      // S = Q K^T
      f32x4 sacc[4];
#pragma unroll
      for (int nt = 0; nt < 4; nt++) sacc[nt] = (f32x4){0.f, 0.f, 0.f, 0.f};
#pragma unroll
      for (int c = 0; c < 2; c++)
#pragma unroll
        for (int nt = 0; nt < 4; nt++) {
          bf16x8 kf = *(const bf16x8*)(&Ks[buf][nt * 16 + li][c * 32 + quad * 8]);
          sacc[nt] = __builtin_amdgcn_mfma_f32_16x16x32_bf16(qf[c], kf, sacc[nt], 0, 0, 0);
        }

      // bias (rl-table) + scale, base-2 domain
      if (u <= 1) {
#pragma unroll
        for (int r = 0; r < 4; r++) {
          const int base = ti[r] - kb - li + 63;
#pragma unroll
          for (int nt = 0; nt < 4; nt++) {
            float rlv = rls[base - nt * 16];
            bool hi = rlv > x0r[r];
            float z = fmaf(rlv, hi ? B1g[r] : B0g[r], hi ? A1e : A0e);
            z = fmaf(sacc[nt][r], SCL, z);
            sacc[nt][r] = (kb + nt * 16 + li > ti[r]) ? -INFF : z;
          }
        }
      } else {
#pragma unroll
        for (int r = 0; r < 4; r++) {
          const int base = ti[r] - kb - li + 63;
#pragma unroll
          for (int nt = 0; nt < 4; nt++) {
            float nd = rls[base - nt * 16] * gI[r];
            int j = 0;
            for (int i = 0; i < u; i++) j += (nd > sXl[i]) ? 1 : 0;
            float z = (fmaf(nd, sBl[j], sAl[j]) + sacc[nt][r] * 0.125f) * LOG2E;
            sacc[nt][r] = (kb + nt * 16 + li > ti[r]) ? -INFF : z;
          }
        }
      }

      // online softmax (base-2)
#pragma unroll
      for (int r = 0; r < 4; r++) {
        float vm = fmaxf(fmaxf(sacc[0][r], sacc[1][r]), fmaxf(sacc[2][r], sacc[3][r]));
#pragma unroll
        for (int off = 1; off < 16; off <<= 1) vm = fmaxf(vm, __shfl_xor(vm, off, 64));
        float mnew = fmaxf(mrow[r], vm);
        float alpha = __builtin_amdgcn_exp2f(mrow[r] - mnew);
        mrow[r] = mnew;
        float s = 0.0f;
#pragma unroll
        for (int nt = 0; nt < 4; nt++) {
          float p = __builtin_amdgcn_exp2f(sacc[nt][r] - mnew);
          sacc[nt][r] = p;
          s += p;
        }
#pragma unroll
        for (int off = 1; off < 16; off <<= 1) s += __shfl_xor(s, off, 64);
        lrow[r] = lrow[r] * alpha + s;
#pragma unroll
        for (int nt = 0; nt < 4; nt++) oacc[nt][r] *= alpha;
      }

      // P -> LDS (C-layout -> A-layout); same-wave rows only, no barrier needed
#pragma unroll
      for (int nt = 0; nt < 4; nt++)
#pragma unroll
        for (int r = 0; r < 4; r++)
          Ps[wave * 16 + quad * 4 + r][nt * 16 + li] = f2bfr(sacc[nt][r]);

      // O += P V
#pragma unroll
      for (int c = 0; c < 2; c++) {
        bf16x8 pf = *(const bf16x8*)(&Ps[wave * 16 + li][c * 32 + quad * 8]);
#pragma unroll
        for (int nt = 0; nt < 4; nt++) {
          bf16x8 vf = *(const bf16x8*)(&Vts[buf][nt * 16 + li][c * 32 + quad * 8]);
          oacc[nt] = __builtin_amdgcn_mfma_f32_16x16x32_bf16(pf, vf, oacc[nt], 0, 0, 0);
        }
      }
    }

    // epilogue
#pragma unroll
    for (int r = 0; r < 4; r++) {
      float inv = 1.0f / lrow[r];
      u16* dst = Y + (size_t)(b * 2048 + ti[r]) * 1024 + h * 64;
#pragma unroll
      for (int nt = 0; nt < 4; nt++) dst[nt * 16 + li] = f2bfr(oacc[nt][r] * inv);
    }
  };

  run_tile(pr);
  run_tile(31 - pr);
}

// ---------------- launcher ----------------
extern "C" void kernel_launch(void* const* d_in, const int* in_sizes, int n_in,
                              void* d_out, int out_size, void* d_ws, size_t ws_size,
                              hipStream_t stream) {
  (void)in_sizes; (void)n_in; (void)out_size; (void)ws_size;
  const float* x = (const float*)d_in[0];
  const float* Wqkv = (const float*)d_in[1];
  const float* bqkv = (const float*)d_in[2];
  const float* Wproj = (const float*)d_in[3];
  const float* bproj = (const float*)d_in[4];
  const float* w1 = (const float*)d_in[5];
  const float* b1 = (const float*)d_in[6];
  const float* w2 = (const float*)d_in[7];
  const float* b2 = (const float*)d_in[8];
  const float* cP = (const float*)d_in[9];
  const float* lP = (const float*)d_in[10];

  char* ws = (char*)d_ws;
  u16* Xbf = (u16*)(ws);                          // 8 MB
  u16* WqkvT = (u16*)(ws + (size_t)(8 << 20));    // 6 MB
  u16* WprojT = (u16*)(ws + (size_t)(14 << 20));  // 2 MB
  u16* Qb = (u16*)(ws + (size_t)(16 << 20));      // 8 MB
  u16* Kb = (u16*)(ws + (size_t)(24 << 20));      // 8 MB
  u16* Vb = (u16*)(ws + (size_t)(32 << 20));      // 8 MB
  u16* Yb = (u16*)(ws + (size_t)(40 << 20));      // 8 MB
  float* IG = (float*)(ws + (size_t)(48 << 20));  // tables
  float* RL = IG + 2048;
  float* SEGX = RL + 2112;
  float* SEGA = SEGX + 32;
  float* SEGB = SEGA + 33 * 16;
  int* SEGU = (int*)(SEGB + 33 * 16);

  k_convert_x<<<4096, 256, 0, stream>>>(x, Xbf, 1048576);
  k_transpose_bf<<<dim3(96, 32), dim3(32, 8), 0, stream>>>(Wqkv, WqkvT, 1024, 3072);
  k_transpose_bf<<<dim3(32, 32), dim3(32, 8), 0, stream>>>(Wproj, WprojT, 1024, 1024);
  k_tables<<<9, 256, 0, stream>>>(cP, lP, IG, RL);
  k_segments<<<1, 64, 0, stream>>>(w1, b1, w2, b2, SEGX, SEGA, SEGB, SEGU);

  k_gemm<0><<<dim3(24, 32), 256, 0, stream>>>(Xbf, WqkvT, bqkv, nullptr, Qb, Kb, Vb,
                                              4096, 3072, 1024);
  k_attn<<<dim3(16, 16, 2), 256, 0, stream>>>(Qb, Kb, Vb, Yb, IG, RL, SEGX, SEGA, SEGB, SEGU);
  k_gemm<1><<<dim3(8, 32), 256, 0, stream>>>(Yb, WprojT, bproj, (float*)d_out, nullptr, nullptr,
                                             nullptr, 4096, 1024, 1024);
}

// Round 3
// 243.535 us; speedup vs baseline: 1.2797x; 1.0525x over previous
//
#include <hip/hip_runtime.h>
#include <cstdint>

typedef unsigned short u16;
typedef unsigned int u32;

typedef short bf16x8 __attribute__((ext_vector_type(8)));
typedef float f32x4 __attribute__((ext_vector_type(4)));

#define LN2 0.69314718055994530942f
#define LOG2E 1.44269504088896340736f
#define INFF __builtin_inff()

__device__ __forceinline__ u16 f2bf(float f) {
  u32 u = __float_as_uint(f);
  u = (u + 0x7fffu + ((u >> 16) & 1u)) >> 16;
  return (u16)u;
}
__device__ __forceinline__ u16 f2bfr(float f) {
  return (u16)((__float_as_uint(f) + 0x8000u) >> 16);
}
// pack two rounded bf16 into one u32: lo from a, hi from b (3 VALU)
__device__ __forceinline__ u32 pack2bf(float a, float b) {
  u32 ta = __float_as_uint(a) + 0x8000u;
  u32 tb = __float_as_uint(b) + 0x8000u;
  return __builtin_amdgcn_perm(tb, ta, 0x07060302u);
}

#if __has_builtin(__builtin_amdgcn_global_load_lds)
#define HAVE_GLDS 1
__device__ __forceinline__ void glds16(const u16* g, u16* l) {
  __builtin_amdgcn_global_load_lds((const __attribute__((address_space(1))) void*)g,
                                   (__attribute__((address_space(3))) void*)l, 16, 0, 0);
}
#else
#define HAVE_GLDS 0
#endif

// ---------------- prep kernels ----------------

__global__ void k_convert_x(const float* __restrict__ in, u16* __restrict__ out, int n4) {
  int i = blockIdx.x * blockDim.x + threadIdx.x;
  if (i < n4) {
    float4 v = ((const float4*)in)[i];
    ushort4 o;
    o.x = f2bf(v.x); o.y = f2bf(v.y); o.z = f2bf(v.z); o.w = f2bf(v.w);
    ((ushort4*)out)[i] = o;
  }
}

__global__ void k_transpose_bf(const float* __restrict__ in, u16* __restrict__ out, int R, int C) {
  __shared__ float t[32][33];
  int c0 = blockIdx.x * 32, r0 = blockIdx.y * 32;
  int tx = threadIdx.x, ty = threadIdx.y;
#pragma unroll
  for (int k = 0; k < 4; k++) t[ty + 8 * k][tx] = in[(size_t)(r0 + ty + 8 * k) * C + c0 + tx];
  __syncthreads();
#pragma unroll
  for (int k = 0; k < 4; k++) out[(size_t)(c0 + ty + 8 * k) * R + r0 + tx] = f2bf(t[tx][ty + 8 * k]);
}

// ig2[t] = ln2 / (ln(|c|*max(t,thr)+1) + 1e-6) ; rl[j] = log2(|c|*max(j-63,0)+1)
__global__ void k_tables(const float* __restrict__ cP, const float* __restrict__ lP,
                         float* __restrict__ ig2, float* __restrict__ rl) {
  int t = blockIdx.x * blockDim.x + threadIdx.x;
  float c = fabsf(cP[0]);
  if (t < 2048) {
    float lm = lP[0];
    float thr = fabsf(lm * 512.0f);
    float pn = fmaxf((float)t, thr);
    float den = logf(c * pn + 1.0f) + 1e-6f;
    ig2[t] = LN2 / den;
  }
  if (t < 2112) {
    int d = t - 63;
    if (d < 0) d = 0;
    rl[t] = log2f(c * (float)d + 1.0f);
  }
}

// Piecewise-linear decomposition of the FIRE MLP.
__global__ void k_segments(const float* __restrict__ w1, const float* __restrict__ b1,
                           const float* __restrict__ w2, const float* __restrict__ b2,
                           float* __restrict__ segX, float* __restrict__ segA,
                           float* __restrict__ segB, int* __restrict__ segU) {
  __shared__ float xs[32];
  __shared__ float srt[32];
  __shared__ float uniq[32];
  __shared__ int uCnt;
  int t = threadIdx.x;
  if (t < 32) {
    float w = w1[t], b = b1[t];
    xs[t] = (w != 0.0f) ? (-b / w) : INFF;
  }
  __syncthreads();
  if (t < 32) {
    float x = xs[t];
    int r = 0;
    for (int v = 0; v < 32; v++) {
      float xv = xs[v];
      if (xv < x || (xv == x && v < t)) r++;
    }
    srt[r] = x;
  }
  __syncthreads();
  if (t == 0) {
    int u = 0;
    for (int i = 0; i < 32; i++) {
      float v = srt[i];
      if (v < 3.0e38f && (u == 0 || v != uniq[u - 1])) uniq[u++] = v;
    }
    uCnt = u;
    segU[0] = u;
  }
  __syncthreads();
  int u = uCnt;
  if (t < u) segX[t] = uniq[t];
  for (int idx = t; idx < (u + 1) * 16; idx += blockDim.x) {
    int j = idx >> 4, h = idx & 15;
    float p;
    if (u == 0) p = 0.0f;
    else if (j == 0) p = uniq[0] - 1.0f;
    else if (j == u) p = uniq[u - 1] + 1.0f;
    else p = 0.5f * (uniq[j - 1] + uniq[j]);
    float A = b2[h], B = 0.0f;
    for (int w = 0; w < 32; w++) {
      float w1w = w1[w], b1w = b1[w], w2wh = w2[w * 16 + h];
      if (w1w != 0.0f) {
        if (fmaf(w1w, p, b1w) > 0.0f) { B += w1w * w2wh; A += b1w * w2wh; }
      } else if (b1w > 0.0f) {
        A += b1w * w2wh;
      }
    }
    segA[j * 16 + h] = A;
    segB[j * 16 + h] = B;
  }
}

// ---------------- GEMM:  C(MxN) = A(MxK) @ BT(NxK)^T ----------------
// m97-style: global_load_lds width-16 staging into unpadded flat LDS, BK=64.
template <int MODE>
__launch_bounds__(256, 3)
__global__ void k_gemm(const u16* __restrict__ A, const u16* __restrict__ BT,
                       const float* __restrict__ bias, float* __restrict__ outF,
                       u16* __restrict__ outQ, u16* __restrict__ outK, u16* __restrict__ outV,
                       int M, int N, int K) {
#if HAVE_GLDS
  __shared__ u16 As[128 * 64];
  __shared__ u16 Bs[128 * 64];
  const int tid = threadIdx.x;
  const int lane = tid & 63, wave = tid >> 6;
  const int li = lane & 15, quad = lane >> 4;
  const int wrow = (wave >> 1) * 64, wcol = (wave & 1) * 64;
  const int rb = blockIdx.y * 128, cb = blockIdx.x * 128;

  f32x4 acc[4][4];
#pragma unroll
  for (int i = 0; i < 4; i++)
#pragma unroll
    for (int j = 0; j < 4; j++) acc[i][j] = (f32x4){0.f, 0.f, 0.f, 0.f};

  // per-thread global source: row (tid>>3) within a 32-row chunk, col (tid&7)*8
  const u16* gA = A + (size_t)(rb + (tid >> 3)) * K + (tid & 7) * 8;
  const u16* gB = BT + (size_t)(cb + (tid >> 3)) * K + (tid & 7) * 8;
  u16* lA = As + wave * 512;  // wave-uniform LDS base; HW adds lane*16B
  u16* lB = Bs + wave * 512;

  for (int k0 = 0; k0 < K; k0 += 64) {
    __syncthreads();
#pragma unroll
    for (int ch = 0; ch < 4; ch++) {
      glds16(gA + (size_t)ch * 32 * K + k0, lA + ch * 2048);
      glds16(gB + (size_t)ch * 32 * K + k0, lB + ch * 2048);
    }
    __syncthreads();
#pragma unroll
    for (int c = 0; c < 2; c++) {
      bf16x8 af[4], bfr[4];
#pragma unroll
      for (int mt = 0; mt < 4; mt++)
        af[mt] = *(const bf16x8*)(&As[(wrow + mt * 16 + li) * 64 + c * 32 + quad * 8]);
#pragma unroll
      for (int nt = 0; nt < 4; nt++)
        bfr[nt] = *(const bf16x8*)(&Bs[(wcol + nt * 16 + li) * 64 + c * 32 + quad * 8]);
#pragma unroll
      for (int mt = 0; mt < 4; mt++)
#pragma unroll
        for (int nt = 0; nt < 4; nt++)
          acc[mt][nt] = __builtin_amdgcn_mfma_f32_16x16x32_bf16(af[mt], bfr[nt], acc[mt][nt], 0, 0, 0);
    }
  }
#else
  // fallback: register-staged path
  __shared__ u16 As[128][72];
  __shared__ u16 Bs[128][72];
  const int tid = threadIdx.x;
  const int lane = tid & 63, wave = tid >> 6;
  const int li = lane & 15, quad = lane >> 4;
  const int wrow = (wave >> 1) * 64, wcol = (wave & 1) * 64;
  const int rb = blockIdx.y * 128, cb = blockIdx.x * 128;
  const int srow = tid >> 1, shalf = tid & 1;

  f32x4 acc[4][4];
#pragma unroll
  for (int i = 0; i < 4; i++)
#pragma unroll
    for (int j = 0; j < 4; j++) acc[i][j] = (f32x4){0.f, 0.f, 0.f, 0.f};

  const u16* gA = A + (size_t)(rb + srow) * K + shalf * 32;
  const u16* gB = BT + (size_t)(cb + srow) * K + shalf * 32;

  for (int k0 = 0; k0 < K; k0 += 64) {
    uint4 a0 = *(const uint4*)(gA + k0);
    uint4 a1 = *(const uint4*)(gA + k0 + 8);
    uint4 a2 = *(const uint4*)(gA + k0 + 16);
    uint4 a3 = *(const uint4*)(gA + k0 + 24);
    uint4 b0 = *(const uint4*)(gB + k0);
    uint4 b1 = *(const uint4*)(gB + k0 + 8);
    uint4 b2v = *(const uint4*)(gB + k0 + 16);
    uint4 b3 = *(const uint4*)(gB + k0 + 24);
    __syncthreads();
    *(uint4*)(&As[srow][shalf * 32]) = a0;
    *(uint4*)(&As[srow][shalf * 32 + 8]) = a1;
    *(uint4*)(&As[srow][shalf * 32 + 16]) = a2;
    *(uint4*)(&As[srow][shalf * 32 + 24]) = a3;
    *(uint4*)(&Bs[srow][shalf * 32]) = b0;
    *(uint4*)(&Bs[srow][shalf * 32 + 8]) = b1;
    *(uint4*)(&Bs[srow][shalf * 32 + 16]) = b2v;
    *(uint4*)(&Bs[srow][shalf * 32 + 24]) = b3;
    __syncthreads();
#pragma unroll
    for (int c = 0; c < 2; c++) {
      bf16x8 af[4], bfr[4];
#pragma unroll
      for (int mt = 0; mt < 4; mt++)
        af[mt] = *(const bf16x8*)(&As[wrow + mt * 16 + li][c * 32 + quad * 8]);
#pragma unroll
      for (int nt = 0; nt < 4; nt++)
        bfr[nt] = *(const bf16x8*)(&Bs[wcol + nt * 16 + li][c * 32 + quad * 8]);
#pragma unroll
      for (int mt = 0; mt < 4; mt++)
#pragma unroll
        for (int nt = 0; nt < 4; nt++)
          acc[mt][nt] = __builtin_amdgcn_mfma_f32_16x16x32_bf16(af[mt], bfr[nt], acc[mt][nt], 0, 0, 0);
    }
  }
#endif

#pragma unroll
  for (int mt = 0; mt < 4; mt++)
#pragma unroll
    for (int nt = 0; nt < 4; nt++)
#pragma unroll
      for (int r = 0; r < 4; r++) {
        int row = rb + wrow + mt * 16 + quad * 4 + r;
        int col = cb + wcol + nt * 16 + li;
        float v = acc[mt][nt][r] + bias[col];
        if (MODE == 0) {
          int b = row >> 11, tt = row & 2047;
          int sel = col >> 10, w = col & 1023, h = w >> 6, dd = w & 63;
          u16* dst = (sel == 0) ? outQ : ((sel == 1) ? outK : outV);
          dst[(size_t)((b * 16 + h) * 2048 + tt) * 64 + dd] = f2bf(v);
        } else {
          outF[(size_t)row * N + col] = v;
        }
      }
}

// ---------------- flash attention, S^T formulation ----------------
// S^T = mfma(A=K, B=Q): lane owns row q=li across all 16 acc elements ->
// per-lane softmax state, 2-shfl reductions, b64 P-store / O-store.
__launch_bounds__(256, 2)
__global__ void k_attn(const u16* __restrict__ Q, const u16* __restrict__ K,
                       const u16* __restrict__ V, u16* __restrict__ Y,
                       const float* __restrict__ ig2, const float* __restrict__ RL,
                       const float* __restrict__ segX, const float* __restrict__ segA,
                       const float* __restrict__ segB, const int* __restrict__ segU) {
  __shared__ u16 Ks[2][64][72];
  __shared__ u16 Vts[2][64][72];  // Vts[d][kk]
  __shared__ u16 Ps[64][72];      // Ps[q][s] (per-wave rows)
  __shared__ float rls[2112];
  __shared__ float sXl[32];
  __shared__ float sAl[33];
  __shared__ float sBl[33];

  const int pr = blockIdx.x, h = blockIdx.y, b = blockIdx.z;
  const int tid = threadIdx.x, lane = tid & 63, wave = tid >> 6;
  const int li = lane & 15, quad = lane >> 4;
  const int bh = b * 16 + h;
  const u16* Qg = Q + (size_t)bh * 2048 * 64;
  const u16* Kg = K + (size_t)bh * 2048 * 64;
  const u16* Vg = V + (size_t)bh * 2048 * 64;

  for (int i = tid; i < 2112; i += 256) rls[i] = RL[i];

  const int u = segU[0];
  float x0 = INFF, A0, B0, A1, B1;
  A0 = segA[h]; B0 = segB[h]; A1 = A0; B1 = B0;
  if (u == 1) { x0 = segX[0]; A1 = segA[16 + h]; B1 = segB[16 + h]; }
  if (u > 1) {
    if (tid < u) sXl[tid] = segX[tid];
    if (tid < u + 1) { sAl[tid] = segA[tid * 16 + h]; sBl[tid] = segB[tid * 16 + h]; }
  }
  const float A0e = A0 * LOG2E, A1e = A1 * LOG2E;
  const float SCL = 0.125f * LOG2E;

  auto run_tile = [&](int qt) {
    const int qw = qt * 64 + wave * 16;
    const int t = qw + li;  // this lane's q-row
    bf16x8 qf[2];
#pragma unroll
    for (int c = 0; c < 2; c++)
      qf[c] = *(const bf16x8*)(Qg + (size_t)t * 64 + c * 32 + quad * 8);

    const float gI = ig2[t];
    const float x0r = x0 / gI;
    const float B0g = B0 * gI * LOG2E, B1g = B1 * gI * LOG2E;
    float mrow = -INFF, lrow = 0.0f;
    f32x4 oacc[4];
#pragma unroll
    for (int nt = 0; nt < 4; nt++) oacc[nt] = (f32x4){0.f, 0.f, 0.f, 0.f};

    // prefetch kt = 0 into registers
    uint4 kv0, kv1, w0, w1;
    {
      const u16* ksrc = Kg + (size_t)(tid >> 2) * 64 + (tid & 3) * 16;
      kv0 = *(const uint4*)(ksrc);
      kv1 = *(const uint4*)(ksrc + 8);
      const u16* vsrc = Vg + (size_t)(2 * (tid & 31)) * 64 + (tid >> 5) * 8;
      w0 = *(const uint4*)(vsrc);
      w1 = *(const uint4*)(vsrc + 64);
    }
    __syncthreads();  // protect LDS buffers from previous tile's readers

    for (int kt = 0; kt <= qt; kt++) {
      const int kb = kt * 64, buf = kt & 1;
      *(uint4*)(&Ks[buf][tid >> 2][(tid & 3) * 16]) = kv0;
      *(uint4*)(&Ks[buf][tid >> 2][(tid & 3) * 16 + 8]) = kv1;
      {
        const int kkp = tid & 31, d0 = (tid >> 5) * 8;
        const u16* pw0 = (const u16*)&w0;
        const u16* pw1 = (const u16*)&w1;
#pragma unroll
        for (int j = 0; j < 8; j++)
          *(u32*)(&Vts[buf][d0 + j][2 * kkp]) = (u32)pw0[j] | ((u32)pw1[j] << 16);
      }
      __syncthreads();
      if (kt < qt) {
        const u16* ksrc = Kg + (size_t)(kb + 64 + (tid >> 2)) * 64 + (tid & 3) * 16;
        kv0 = *(const uint4*)(ksrc);
        kv1 = *(const uint4*)(ksrc + 8);
        const u16* vsrc = Vg + (size_t)(kb + 64 + 2 * (tid & 31)) * 64 + (tid >> 5) * 8;
        w0 = *(const uint4*)(vsrc);
        w1 = *(const uint4*)(vsrc + 64);
      }

      // S^T = K Q^T : sacc[nt] row s = nt*16+quad*4+r, col q = li
      f32x4 sacc[4];
#pragma unroll
      for (int nt = 0; nt < 4; nt++) sacc[nt] = (f32x4){0.f, 0.f, 0.f, 0.f};
#pragma unroll
      for (int c = 0; c < 2; c++)
#pragma unroll
        for (int nt = 0; nt < 4; nt++) {
          bf16x8 kf = *(const bf16x8*)(&Ks[buf][nt * 16 + li][c * 32 + quad * 8]);
          sacc[nt] = __builtin_amdgcn_mfma_f32_16x16x32_bf16(kf, qf[c], sacc[nt], 0, 0, 0);
        }

      // bias: rl index = t - s + 63; per-lane base, immediate offsets
      const int Cbase = t - kb - quad * 4 + 63;  // in [51, 2110]
      const float* rp = &rls[Cbase - 51];
      if (u <= 1) {
        const int lim = Cbase - 63;  // mask when nt*16+r > lim (diagonal only)
#pragma unroll
        for (int nt = 0; nt < 4; nt++)
#pragma unroll
          for (int r = 0; r < 4; r++) {
            float rlv = rp[51 - nt * 16 - r];
            bool hi = rlv > x0r;
            float z = fmaf(rlv, hi ? B1g : B0g, hi ? A1e : A0e);
            z = fmaf(sacc[nt][r], SCL, z);
            if (kt == qt) z = (nt * 16 + r > lim) ? -INFF : z;
            sacc[nt][r] = z;
          }
      } else {
        const int lim = Cbase - 63;
#pragma unroll
        for (int nt = 0; nt < 4; nt++)
#pragma unroll
          for (int r = 0; r < 4; r++) {
            float nd = rp[51 - nt * 16 - r] * gI;
            int j = 0;
            for (int i = 0; i < u; i++) j += (nd > sXl[i]) ? 1 : 0;
            float z = (fmaf(nd, sBl[j], sAl[j]) + sacc[nt][r] * 0.125f) * LOG2E;
            if (kt == qt) z = (nt * 16 + r > lim) ? -INFF : z;
            sacc[nt][r] = z;
          }
      }

      // per-lane online softmax (row q = li), reduce across quads only
      float vm = -INFF;
#pragma unroll
      for (int nt = 0; nt < 4; nt++)
#pragma unroll
        for (int r = 0; r < 4; r++) vm = fmaxf(vm, sacc[nt][r]);
      vm = fmaxf(vm, __shfl_xor(vm, 16, 64));
      vm = fmaxf(vm, __shfl_xor(vm, 32, 64));
      float mnew = fmaxf(mrow, vm);
      float alpha = __builtin_amdgcn_exp2f(mrow - mnew);
      mrow = mnew;
      float s = 0.0f;
#pragma unroll
      for (int nt = 0; nt < 4; nt++)
#pragma unroll
        for (int r = 0; r < 4; r++) {
          float p = __builtin_amdgcn_exp2f(sacc[nt][r] - mnew);
          sacc[nt][r] = p;
          s += p;
        }
      s += __shfl_xor(s, 16, 64);
      s += __shfl_xor(s, 32, 64);
      lrow = lrow * alpha + s;
#pragma unroll
      for (int nt = 0; nt < 4; nt++)
#pragma unroll
        for (int r = 0; r < 4; r++) oacc[nt][r] *= alpha;

      // P^T -> Ps[q][s]: 4 consecutive r per (nt) -> b64 writes (same-wave rows)
      const int prow = wave * 16 + li;
#pragma unroll
      for (int nt = 0; nt < 4; nt++) {
        uint2 pk;
        pk.x = pack2bf(sacc[nt][0], sacc[nt][1]);
        pk.y = pack2bf(sacc[nt][2], sacc[nt][3]);
        *(uint2*)(&Ps[prow][nt * 16 + quad * 4]) = pk;
      }

      // O^T += V^T P^T : oacc[nt] row d = nt*16+quad*4+r, col q = li
#pragma unroll
      for (int c = 0; c < 2; c++) {
        bf16x8 pf = *(const bf16x8*)(&Ps[wave * 16 + li][c * 32 + quad * 8]);
#pragma unroll
        for (int nt = 0; nt < 4; nt++) {
          bf16x8 vf = *(const bf16x8*)(&Vts[buf][nt * 16 + li][c * 32 + quad * 8]);
          oacc[nt] = __builtin_amdgcn_mfma_f32_16x16x32_bf16(vf, pf, oacc[nt], 0, 0, 0);
        }
      }
    }

    // epilogue: O^T element (d = nt*16+quad*4+r, q = li) -> Y[b][t][h*64+d]
    float inv = 1.0f / lrow;
    u16* dst = Y + (size_t)(b * 2048 + t) * 1024 + h * 64 + quad * 4;
#pragma unroll
    for (int nt = 0; nt < 4; nt++) {
      uint2 pk;
      pk.x = pack2bf(oacc[nt][0] * inv, oacc[nt][1] * inv);
      pk.y = pack2bf(oacc[nt][2] * inv, oacc[nt][3] * inv);
      *(uint2*)(dst + nt * 16) = pk;
    }
  };

  run_tile(pr);
  run_tile(31 - pr);
}

// ---------------- launcher ----------------
extern "C" void kernel_launch(void* const* d_in, const int* in_sizes, int n_in,
                              void* d_out, int out_size, void* d_ws, size_t ws_size,
                              hipStream_t stream) {
  (void)in_sizes; (void)n_in; (void)out_size; (void)ws_size;
  const float* x = (const float*)d_in[0];
  const float* Wqkv = (const float*)d_in[1];
  const float* bqkv = (const float*)d_in[2];
  const float* Wproj = (const float*)d_in[3];
  const float* bproj = (const float*)d_in[4];
  const float* w1 = (const float*)d_in[5];
  const float* b1 = (const float*)d_in[6];
  const float* w2 = (const float*)d_in[7];
  const float* b2 = (const float*)d_in[8];
  const float* cP = (const float*)d_in[9];
  const float* lP = (const float*)d_in[10];

  char* ws = (char*)d_ws;
  u16* Xbf = (u16*)(ws);                          // 8 MB
  u16* WqkvT = (u16*)(ws + (size_t)(8 << 20));    // 6 MB
  u16* WprojT = (u16*)(ws + (size_t)(14 << 20));  // 2 MB
  u16* Qb = (u16*)(ws + (size_t)(16 << 20));      // 8 MB
  u16* Kb = (u16*)(ws + (size_t)(24 << 20));      // 8 MB
  u16* Vb = (u16*)(ws + (size_t)(32 << 20));      // 8 MB
  u16* Yb = (u16*)(ws + (size_t)(40 << 20));      // 8 MB
  float* IG = (float*)(ws + (size_t)(48 << 20));  // tables
  float* RL = IG + 2048;
  float* SEGX = RL + 2112;
  float* SEGA = SEGX + 32;
  float* SEGB = SEGA + 33 * 16;
  int* SEGU = (int*)(SEGB + 33 * 16);

  k_convert_x<<<4096, 256, 0, stream>>>(x, Xbf, 1048576);
  k_transpose_bf<<<dim3(96, 32), dim3(32, 8), 0, stream>>>(Wqkv, WqkvT, 1024, 3072);
  k_transpose_bf<<<dim3(32, 32), dim3(32, 8), 0, stream>>>(Wproj, WprojT, 1024, 1024);
  k_tables<<<9, 256, 0, stream>>>(cP, lP, IG, RL);
  k_segments<<<1, 64, 0, stream>>>(w1, b1, w2, b2, SEGX, SEGA, SEGB, SEGU);

  k_gemm<0><<<dim3(24, 32), 256, 0, stream>>>(Xbf, WqkvT, bqkv, nullptr, Qb, Kb, Vb,
                                              4096, 3072, 1024);
  k_attn<<<dim3(16, 16, 2), 256, 0, stream>>>(Qb, Kb, Vb, Yb, IG, RL, SEGX, SEGA, SEGB, SEGU);
  k_gemm<1><<<dim3(8, 32), 256, 0, stream>>>(Yb, WprojT, bproj, (float*)d_out, nullptr, nullptr,
                                             nullptr, 4096, 1024, 1024);
}